// Round 1
// baseline (197.133 us; speedup 1.0000x reference)
//
#include <hip/hip_runtime.h>

// SSIM loss, fused single-pass implementation.
// pred/target: (128,1,320,320) f32. Output: scalar f32 = 1 - mean(ssim_map).
// Separable 11-tap Gaussian (sigma=1.5), zero-padded SAME (matches reference
// jax.lax.conv_general_dilated with explicit padding).

namespace {
constexpr int TW = 64;            // tile width  (outputs)
constexpr int TH = 16;            // tile height (outputs)
constexpr int HALO = 5;
constexpr int IW = 76;            // 74 used (TW+10), padded to /4 for float4
constexpr int IW_USED = TW + 2 * HALO;  // 74
constexpr int IH = TH + 2 * HALO;       // 26
constexpr int W = 320, H = 320, B = 128;
constexpr int TX = W / TW;        // 5
constexpr int TY = H / TH;        // 20
constexpr int NBLK = B * TX * TY; // 12800
constexpr float C1 = 0.01f * 0.01f;
constexpr float C2 = 0.03f * 0.03f;
}

__global__ __launch_bounds__(256) void ssim_main(
    const float* __restrict__ pred, const float* __restrict__ targ,
    float* __restrict__ out) {
  __shared__ float sp[IH][IW];
  __shared__ float st[IH][IW];
  __shared__ float hb[5][IH][TW];   // h-blurred: mu_x, mu_y, E[xx], E[yy], E[xy]
  __shared__ float wsum[4];

  const int tid = threadIdx.x;
  const int bid = blockIdx.x;
  const int img = bid / (TX * TY);
  const int t   = bid % (TX * TY);
  const int tx  = t % TX;
  const int ty  = t / TX;
  const int gx0 = tx * TW - HALO;
  const int gy0 = ty * TH - HALO;

  const float* __restrict__ P = pred + (size_t)img * (W * H);
  const float* __restrict__ T = targ + (size_t)img * (W * H);

  // Gaussian weights, computed as in reference (f32 exp, normalized).
  float w[11];
  {
    float s = 0.f;
#pragma unroll
    for (int i = 0; i < 11; ++i) {
      float d = (float)(i - 5) / 1.5f;
      w[i] = expf(-0.5f * d * d);
      s += w[i];
    }
#pragma unroll
    for (int i = 0; i < 11; ++i) w[i] /= s;
  }

  // ---- stage inputs (tile + halo) with zero padding ----
  for (int idx = tid; idx < IH * IW; idx += 256) {
    const int iy = idx / IW;
    const int ix = idx - iy * IW;
    const int gx = gx0 + ix;
    const int gy = gy0 + iy;
    float p = 0.f, tv = 0.f;
    if (ix < IW_USED && gx >= 0 && gx < W && gy >= 0 && gy < H) {
      const int gofs = gy * W + gx;
      p  = P[gofs];
      tv = T[gofs];
    }
    sp[iy][ix] = p;
    st[iy][ix] = tv;
  }
  __syncthreads();

  // ---- horizontal pass: 26 rows x 16 x-quads; 5 channels per task ----
  for (int task = tid; task < IH * 16; task += 256) {
    const int y  = task >> 4;
    const int ix = (task & 15) * 4;

    float vp[16], vt[16];
    *(float4*)&vp[0]  = *(const float4*)&sp[y][ix];
    *(float4*)&vp[4]  = *(const float4*)&sp[y][ix + 4];
    *(float4*)&vp[8]  = *(const float4*)&sp[y][ix + 8];
    *(float4*)&vp[12] = *(const float4*)&sp[y][ix + 12];
    *(float4*)&vt[0]  = *(const float4*)&st[y][ix];
    *(float4*)&vt[4]  = *(const float4*)&st[y][ix + 4];
    *(float4*)&vt[8]  = *(const float4*)&st[y][ix + 8];
    *(float4*)&vt[12] = *(const float4*)&st[y][ix + 12];

    float o0[4] = {0,0,0,0}, o1[4] = {0,0,0,0}, o2[4] = {0,0,0,0};
    float o3[4] = {0,0,0,0}, o4[4] = {0,0,0,0};
#pragma unroll
    for (int k = 0; k < 11; ++k) {
      const float wk = w[k];
#pragma unroll
      for (int j = 0; j < 4; ++j) {
        const float a = vp[k + j];
        const float b = vt[k + j];
        const float wa = wk * a;
        const float wb = wk * b;
        o0[j] = fmaf(wk, a, o0[j]);
        o1[j] = fmaf(wk, b, o1[j]);
        o2[j] = fmaf(wa, a, o2[j]);
        o3[j] = fmaf(wb, b, o3[j]);
        o4[j] = fmaf(wa, b, o4[j]);
      }
    }
    *(float4*)&hb[0][y][ix] = make_float4(o0[0], o0[1], o0[2], o0[3]);
    *(float4*)&hb[1][y][ix] = make_float4(o1[0], o1[1], o1[2], o1[3]);
    *(float4*)&hb[2][y][ix] = make_float4(o2[0], o2[1], o2[2], o2[3]);
    *(float4*)&hb[3][y][ix] = make_float4(o3[0], o3[1], o3[2], o3[3]);
    *(float4*)&hb[4][y][ix] = make_float4(o4[0], o4[1], o4[2], o4[3]);
  }
  __syncthreads();

  // ---- vertical pass + SSIM ----
  const int x  = tid & 63;
  const int yg = tid >> 6;        // 0..3, each does 4 consecutive output rows
  const int yb = yg * 4;

  float mx[4] = {0,0,0,0}, my[4] = {0,0,0,0};
  float exx[4] = {0,0,0,0}, eyy[4] = {0,0,0,0}, exy[4] = {0,0,0,0};
#pragma unroll
  for (int r = 0; r < 14; ++r) {
    const float a = hb[0][yb + r][x];
    const float b = hb[1][yb + r][x];
    const float c = hb[2][yb + r][x];
    const float d = hb[3][yb + r][x];
    const float e = hb[4][yb + r][x];
#pragma unroll
    for (int j = 0; j < 4; ++j) {
      const int k = r - j;
      if (k >= 0 && k < 11) {
        const float wk = w[k];
        mx[j]  = fmaf(wk, a, mx[j]);
        my[j]  = fmaf(wk, b, my[j]);
        exx[j] = fmaf(wk, c, exx[j]);
        eyy[j] = fmaf(wk, d, eyy[j]);
        exy[j] = fmaf(wk, e, exy[j]);
      }
    }
  }

  float accs = 0.f;
#pragma unroll
  for (int j = 0; j < 4; ++j) {
    const float mux = mx[j], muy = my[j];
    const float mxx = mux * mux, myy = muy * muy, mxy = mux * muy;
    const float vx  = exx[j] - mxx;
    const float vy  = eyy[j] - myy;
    const float vxy = exy[j] - mxy;
    const float num = (2.f * mxy + C1) * (2.f * vxy + C2);
    const float den = (mxx + myy + C1) * (vx + vy + C2);
    accs += num / den;
  }

  // ---- reduce: wave -> block -> global ----
#pragma unroll
  for (int off = 32; off > 0; off >>= 1)
    accs += __shfl_down(accs, off, 64);
  if ((tid & 63) == 0) wsum[tid >> 6] = accs;
  __syncthreads();
  if (tid == 0) {
    const float bsum = wsum[0] + wsum[1] + wsum[2] + wsum[3];
    atomicAdd(out, bsum);
  }
}

__global__ void ssim_final(float* __restrict__ out) {
  const float n = (float)((long long)B * W * H);
  out[0] = 1.f - out[0] / n;
}

extern "C" void kernel_launch(void* const* d_in, const int* in_sizes, int n_in,
                              void* d_out, int out_size, void* d_ws, size_t ws_size,
                              hipStream_t stream) {
  (void)in_sizes; (void)n_in; (void)d_ws; (void)ws_size; (void)out_size;
  const float* pred = (const float*)d_in[0];
  const float* targ = (const float*)d_in[1];
  float* out = (float*)d_out;

  hipMemsetAsync(out, 0, sizeof(float), stream);
  ssim_main<<<dim3(NBLK), dim3(256), 0, stream>>>(pred, targ, out);
  ssim_final<<<1, 1, 0, stream>>>(out);
}

// Round 2
// 104.861 us; speedup vs baseline: 1.8799x; 1.8799x over previous
//
#include <hip/hip_runtime.h>
#include <hip/hip_bf16.h>

// SSIM loss v2: barrier-free, LDS-free wave-per-stripe design.
// Each 64-lane wave owns a full-width (320-col) stripe of TH output rows of
// one image; lane l owns columns 5l..5l+4. Vertical 11-tap Gaussian via a
// sliding register ring (p,t packed bf16x2), horizontal 11-tap via +-1 lane
// shuffles, SSIM + reduction in-register, one atomicAdd per wave.

namespace {
constexpr int W = 320, H = 320, B = 128;
constexpr int TH = 16;                  // output rows per stripe
constexpr int NSTRIPE = H / TH;         // 20
constexpr int NBLK = B * NSTRIPE;       // 2560 one-wave blocks
constexpr float C1 = 0.01f * 0.01f;
constexpr float C2 = 0.03f * 0.03f;
}

__device__ __forceinline__ float rcp_fast(float x) {
  float r;
  asm("v_rcp_f32 %0, %1" : "=v"(r) : "v"(x));
  return r;
}

__global__ __launch_bounds__(64, 3) void ssim_stripe(
    const float* __restrict__ pred, const float* __restrict__ targ,
    float* __restrict__ out) {
  const int lane = threadIdx.x;         // 0..63
  const int bid  = blockIdx.x;
  const int img  = bid / NSTRIPE;
  const int y0   = (bid % NSTRIPE) * TH;

  const float* __restrict__ P = pred + (size_t)img * (W * H) + 5 * lane;
  const float* __restrict__ T = targ + (size_t)img * (W * H) + 5 * lane;

  // 11-tap Gaussian weights (f32, as in reference), forced into SGPRs.
  float w[11];
  {
    float wv[11];
    float s = 0.f;
#pragma unroll
    for (int i = 0; i < 11; ++i) {
      float d = (float)(i - 5) / 1.5f;
      wv[i] = expf(-0.5f * d * d);
      s += wv[i];
    }
    const float inv = 1.f / s;
#pragma unroll
    for (int i = 0; i < 11; ++i)
      w[i] = __uint_as_float(
          __builtin_amdgcn_readfirstlane(__float_as_uint(wv[i] * inv)));
  }

  // ---- sliding ring: 11 rows x 5 cols, (p,t) packed as bf16x2 ----
  unsigned ring[11][5];
  unsigned nxt[5];

  auto load_row = [&](int row, unsigned dst[5]) {
    if (row >= 0 && row < H) {
      const float* __restrict__ pr = P + row * W;
      const float* __restrict__ tr = T + row * W;
#pragma unroll
      for (int c = 0; c < 5; ++c) {
        union { __hip_bfloat162 h; unsigned u; } cv;
        cv.h = __float22bfloat162_rn(make_float2(pr[c], tr[c]));
        dst[c] = cv.u;   // lo 16 = p, hi 16 = t
      }
    } else {
#pragma unroll
      for (int c = 0; c < 5; ++c) dst[c] = 0u;
    }
  };

  // Preload: slots 1..10 get rows y0-5 .. y0+4; nxt gets row y0+5.
#pragma unroll
  for (int j = 1; j <= 10; ++j) load_row(y0 - 6 + j, ring[j]);
  load_row(y0 + 5, nxt);

  // h-blur helper: 11-tap over own 5 cols + 5 from each neighbor lane.
  auto hblur = [&](const float v[5], float o[5]) {
    float ext[15];
#pragma unroll
    for (int c = 0; c < 5; ++c) ext[5 + c] = v[c];
#pragma unroll
    for (int c = 0; c < 5; ++c) {
      const float lv = __shfl_up(v[c], 1, 64);
      ext[c] = (lane >= 1) ? lv : 0.f;          // cols <0 are zero-pad
      const float rv = __shfl_down(v[c], 1, 64);
      ext[10 + c] = (lane <= 62) ? rv : 0.f;    // cols >=320 are zero-pad
    }
#pragma unroll
    for (int c = 0; c < 5; ++c) {
      float a = 0.f;
#pragma unroll
      for (int k = 0; k < 11; ++k) a = fmaf(w[k], ext[c + k], a);
      o[c] = a;
    }
  };

  float acc = 0.f;

#pragma unroll 1
  for (int oy = 0; oy < TH; ++oy) {
    // slide window: drop oldest, insert prefetched row, prefetch next.
#pragma unroll
    for (int k = 0; k < 10; ++k)
#pragma unroll
      for (int c = 0; c < 5; ++c) ring[k][c] = ring[k + 1][c];
#pragma unroll
    for (int c = 0; c < 5; ++c) ring[10][c] = nxt[c];
    load_row(y0 + oy + 6, nxt);   // latency hidden under this row's compute

    // ---- vertical 11-tap blur, 5 channels, 5 cols ----
    float vmp[5] = {0, 0, 0, 0, 0}, vmt[5] = {0, 0, 0, 0, 0};
    float vpp[5] = {0, 0, 0, 0, 0}, vtt[5] = {0, 0, 0, 0, 0};
    float vpt[5] = {0, 0, 0, 0, 0};
#pragma unroll
    for (int k = 0; k < 11; ++k) {
      const float wk = w[k];
#pragma unroll
      for (int c = 0; c < 5; ++c) {
        const unsigned r = ring[k][c];
        const float p = __uint_as_float(r << 16);
        const float t = __uint_as_float(r & 0xffff0000u);
        const float wp = wk * p;
        const float wt = wk * t;
        vmp[c] = fmaf(wk, p, vmp[c]);
        vmt[c] = fmaf(wk, t, vmt[c]);
        vpp[c] = fmaf(wp, p, vpp[c]);
        vtt[c] = fmaf(wt, t, vtt[c]);
        vpt[c] = fmaf(wp, t, vpt[c]);
      }
    }

    // ---- horizontal 11-tap blur per channel ----
    float mx[5], my[5], exx[5], eyy[5], exy[5];
    hblur(vmp, mx);
    hblur(vmt, my);
    hblur(vpp, exx);
    hblur(vtt, eyy);
    hblur(vpt, exy);

    // ---- SSIM map + accumulate ----
#pragma unroll
    for (int c = 0; c < 5; ++c) {
      const float mux = mx[c], muy = my[c];
      const float mxx = mux * mux, myy = muy * muy, mxy = mux * muy;
      const float vx  = exx[c] - mxx;
      const float vy  = eyy[c] - myy;
      const float vxy = exy[c] - mxy;
      const float num = (2.f * mxy + C1) * (2.f * vxy + C2);
      const float den = (mxx + myy + C1) * (vx + vy + C2);
      acc = fmaf(num, rcp_fast(den), acc);
    }
  }

  // ---- wave reduce + one atomic per wave ----
#pragma unroll
  for (int off = 32; off > 0; off >>= 1)
    acc += __shfl_down(acc, off, 64);
  if (lane == 0) atomicAdd(out, acc);
}

__global__ void ssim_final(float* __restrict__ out) {
  const float n = (float)((long long)B * W * H);
  out[0] = 1.f - out[0] / n;
}

extern "C" void kernel_launch(void* const* d_in, const int* in_sizes, int n_in,
                              void* d_out, int out_size, void* d_ws, size_t ws_size,
                              hipStream_t stream) {
  (void)in_sizes; (void)n_in; (void)d_ws; (void)ws_size; (void)out_size;
  const float* pred = (const float*)d_in[0];
  const float* targ = (const float*)d_in[1];
  float* out = (float*)d_out;

  hipMemsetAsync(out, 0, sizeof(float), stream);
  ssim_stripe<<<dim3(NBLK), dim3(64), 0, stream>>>(pred, targ, out);
  ssim_final<<<1, 1, 0, stream>>>(out);
}

// Round 3
// 103.809 us; speedup vs baseline: 1.8990x; 1.0101x over previous
//
#include <hip/hip_runtime.h>

// SSIM loss v3: wave-per-stripe, f16 row-pair ring + v_dot2_f32_f16 vertical
// blur, 2 output rows per iteration, horizontal blur via lane shuffles.
// Each 64-lane wave owns a full-width (320-col) stripe of TH=10 output rows;
// lane l owns columns 5l..5l+4.

namespace {
constexpr int W = 320, H = 320, B = 128;
constexpr int TH = 10;                  // output rows per stripe (even!)
constexpr int NSTRIPE = H / TH;         // 32
constexpr int NBLK = B * NSTRIPE;       // 4096 one-wave blocks
constexpr float C1 = 0.01f * 0.01f;
constexpr float C2 = 0.03f * 0.03f;
}

typedef _Float16 h2 __attribute__((ext_vector_type(2)));

__device__ __forceinline__ float fdot2(h2 a, h2 b, float c) {
#if __has_builtin(__builtin_amdgcn_fdot2)
  return __builtin_amdgcn_fdot2(a, b, c, false);
#else
  return fmaf((float)a.x, (float)b.x, fmaf((float)a.y, (float)b.y, c));
#endif
}

__device__ __forceinline__ float rcp_fast(float x) {
  float r;
  asm("v_rcp_f32 %0, %1" : "=v"(r) : "v"(x));
  return r;
}

__device__ __forceinline__ h2 rfl_h2(h2 v) {
  int u = __builtin_amdgcn_readfirstlane(__builtin_bit_cast(int, v));
  return __builtin_bit_cast(h2, u);
}

__global__ __launch_bounds__(64, 4) void ssim_stripe(
    const float* __restrict__ pred, const float* __restrict__ targ,
    float* __restrict__ out) {
  const int lane = threadIdx.x;
  const int bid  = blockIdx.x;
  const int img  = bid / NSTRIPE;
  const int y0   = (bid % NSTRIPE) * TH;

  const float* __restrict__ P = pred + (size_t)img * (W * H) + 5 * lane;
  const float* __restrict__ T = targ + (size_t)img * (W * H) + 5 * lane;

  // ---- Gaussian weights: f32 (h-blur, SGPR) + packed f16 pairs (v-blur) ----
  float w[11];
  h2 wA[6], wB[6];
  {
    float wv[11];
    float s = 0.f;
#pragma unroll
    for (int i = 0; i < 11; ++i) {
      float d = (float)(i - 5) / 1.5f;
      wv[i] = expf(-0.5f * d * d);
      s += wv[i];
    }
    const float inv = 1.f / s;
#pragma unroll
    for (int i = 0; i < 11; ++i) {
      wv[i] *= inv;
      w[i] = __uint_as_float(
          __builtin_amdgcn_readfirstlane(__float_as_uint(wv[i])));
    }
    _Float16 wh[11];
#pragma unroll
    for (int i = 0; i < 11; ++i) wh[i] = (_Float16)wv[i];
    // Row y taps rows y-5..y+5; ring pair j covers rows (y-5+2j, y-4+2j).
#pragma unroll
    for (int j = 0; j < 5; ++j) wA[j] = rfl_h2(h2{wh[2 * j], wh[2 * j + 1]});
    wA[5] = rfl_h2(h2{wh[10], (_Float16)0.f});
    // Row y+1 taps rows y-4..y+6.
    wB[0] = rfl_h2(h2{(_Float16)0.f, wh[0]});
#pragma unroll
    for (int j = 1; j < 6; ++j) wB[j] = rfl_h2(h2{wh[2 * j - 1], wh[2 * j]});
  }

  // ---- ring: 6 row-pairs x 5 cols per signal, f16x2 (rowA,rowB) ----
  h2 rp[6][5], rt[6][5], np[5], nt[5];

  auto load_row2 = [&](int r, float fp[5], float ft[5]) {
    if (r >= 0 && r < H) {           // wave-uniform branch
      const float* __restrict__ pr = P + r * W;
      const float* __restrict__ tr = T + r * W;
#pragma unroll
      for (int c = 0; c < 5; ++c) { fp[c] = pr[c]; ft[c] = tr[c]; }
    } else {
#pragma unroll
      for (int c = 0; c < 5; ++c) { fp[c] = 0.f; ft[c] = 0.f; }
    }
  };
  auto load_pair = [&](int r, h2 dp[5], h2 dt[5]) {
    float pa[5], ta[5], pb[5], tb[5];
    load_row2(r, pa, ta);
    load_row2(r + 1, pb, tb);
#pragma unroll
    for (int c = 0; c < 5; ++c) {
      dp[c] = h2{(_Float16)pa[c], (_Float16)pb[c]};
      dt[c] = h2{(_Float16)ta[c], (_Float16)tb[c]};
    }
  };

  // Preload: ring[1..5] <- rows y0-5..y0+4; nxt <- (y0+5, y0+6).
#pragma unroll
  for (int j = 1; j <= 5; ++j) load_pair(y0 - 7 + 2 * j, rp[j], rt[j]);
  load_pair(y0 + 5, np, nt);

  // ---- h-blur: 11-tap over own 5 cols + 5 from each neighbor lane ----
  auto hblur = [&](const float v[5], float o[5]) {
    float ext[15];
#pragma unroll
    for (int c = 0; c < 5; ++c) ext[5 + c] = v[c];
#pragma unroll
    for (int c = 0; c < 5; ++c) {
      const float lv = __shfl_up(v[c], 1, 64);
      ext[c] = (lane >= 1) ? lv : 0.f;
      const float rv = __shfl_down(v[c], 1, 64);
      ext[10 + c] = (lane <= 62) ? rv : 0.f;
    }
#pragma unroll
    for (int c = 0; c < 5; ++c) {
      float a = 0.f;
#pragma unroll
      for (int k = 0; k < 11; ++k) a = fmaf(w[k], ext[c + k], a);
      o[c] = a;
    }
  };

  float acc = 0.f;

  auto process_row = [&](const h2 wv[6]) {
    float vmp[5], vmt[5], vpp[5], vtt[5], vpt[5];
#pragma unroll
    for (int c = 0; c < 5; ++c) {
      float mp = 0.f, mt = 0.f, pp = 0.f, tt = 0.f, pt = 0.f;
#pragma unroll
      for (int j = 0; j < 6; ++j) {
        const h2 a = rp[j][c];
        const h2 b = rt[j][c];
        const h2 wp = wv[j] * a;   // v_pk_mul_f16
        const h2 wt = wv[j] * b;
        mp = fdot2(wv[j], a, mp);
        mt = fdot2(wv[j], b, mt);
        pp = fdot2(wp, a, pp);
        tt = fdot2(wt, b, tt);
        pt = fdot2(wp, b, pt);
      }
      vmp[c] = mp; vmt[c] = mt; vpp[c] = pp; vtt[c] = tt; vpt[c] = pt;
    }
    float mx[5], my[5], exx[5], eyy[5], exy[5];
    hblur(vmp, mx);
    hblur(vmt, my);
    hblur(vpp, exx);
    hblur(vtt, eyy);
    hblur(vpt, exy);
#pragma unroll
    for (int c = 0; c < 5; ++c) {
      const float mux = mx[c], muy = my[c];
      const float mxx = mux * mux, myy = muy * muy, mxy = mux * muy;
      const float vx  = exx[c] - mxx;
      const float vy  = eyy[c] - myy;
      const float vxy = exy[c] - mxy;
      const float num = (2.f * mxy + C1) * (2.f * vxy + C2);
      const float den = (mxx + myy + C1) * (vx + vy + C2);
      acc = fmaf(num, rcp_fast(den), acc);
    }
  };

#pragma unroll 1
  for (int it = 0; it < TH / 2; ++it) {
    const int y = y0 + 2 * it;
    // slide ring by one pair; insert prefetched pair; prefetch next.
#pragma unroll
    for (int j = 0; j < 5; ++j)
#pragma unroll
      for (int c = 0; c < 5; ++c) { rp[j][c] = rp[j + 1][c]; rt[j][c] = rt[j + 1][c]; }
#pragma unroll
    for (int c = 0; c < 5; ++c) { rp[5][c] = np[c]; rt[5][c] = nt[c]; }
    load_pair(y + 7, np, nt);

    process_row(wA);   // output row y
    process_row(wB);   // output row y+1
  }

  // ---- wave reduce + one atomic per wave ----
#pragma unroll
  for (int off = 32; off > 0; off >>= 1)
    acc += __shfl_down(acc, off, 64);
  if (lane == 0) atomicAdd(out, acc);
}

__global__ void ssim_final(float* __restrict__ out) {
  const float n = (float)((long long)B * W * H);
  out[0] = 1.f - out[0] / n;
}

extern "C" void kernel_launch(void* const* d_in, const int* in_sizes, int n_in,
                              void* d_out, int out_size, void* d_ws, size_t ws_size,
                              hipStream_t stream) {
  (void)in_sizes; (void)n_in; (void)d_ws; (void)ws_size; (void)out_size;
  const float* pred = (const float*)d_in[0];
  const float* targ = (const float*)d_in[1];
  float* out = (float*)d_out;

  hipMemsetAsync(out, 0, sizeof(float), stream);
  ssim_stripe<<<dim3(NBLK), dim3(64), 0, stream>>>(pred, targ, out);
  ssim_final<<<1, 1, 0, stream>>>(out);
}

// Round 4
// 64.299 us; speedup vs baseline: 3.0659x; 1.6145x over previous
//
#include <hip/hip_runtime.h>

// SSIM loss v4: wave-per-stripe (TH=8), 4-wave blocks, spill-proof macro
// staging, raw-f32 prefetch (pack deferred one iteration), row-pair-packed
// f16 horizontal blur (pk_fma) with halved shuffle count, spread atomics.

namespace {
constexpr int W = 320, H = 320, B = 128;
constexpr int TH = 8;
constexpr int NSTRIPE = H / TH;     // 40
constexpr int WPB = 4;              // waves per block
constexpr int NWAVE = B * NSTRIPE;  // 5120
constexpr int NBLK = NWAVE / WPB;   // 1280
constexpr int ITERS = TH / 2;       // 4
constexpr float C1 = 1.0e-4f;
constexpr float C2 = 9.0e-4f;
constexpr int NSLOT = 128;          // partial-sum slots (pow2)
constexpr int SSTR = 16;            // floats between slots (64 B)
}

typedef _Float16 h2 __attribute__((ext_vector_type(2)));

__device__ __forceinline__ float fdot2f(h2 a, h2 b, float c) {
#if __has_builtin(__builtin_amdgcn_fdot2)
  return __builtin_amdgcn_fdot2(a, b, c, false);
#else
  return fmaf((float)a.x, (float)b.x, fmaf((float)a.y, (float)b.y, c));
#endif
}

__device__ __forceinline__ float rcpf(float x) {
  float r;
  asm("v_rcp_f32 %0, %1" : "=v"(r) : "v"(x));
  return r;
}

__device__ __forceinline__ h2 pack2(float a, float b) {
  return h2{(_Float16)a, (_Float16)b};
}

// Load one row-pair's 5 cols of both signals into f32 arrays (zero-padded).
#define LOADP_RAW(ROW, A0, B0, A1, B1)                                        \
  do {                                                                        \
    const int r0_ = (ROW);                                                    \
    if (r0_ >= 0 && r0_ < H) {                                                \
      const float* p_ = P + r0_ * W;                                          \
      const float* t_ = T + r0_ * W;                                          \
      _Pragma("unroll") for (int c_ = 0; c_ < 5; ++c_) {                      \
        A0[c_] = p_[c_]; B0[c_] = t_[c_];                                     \
      }                                                                       \
    } else {                                                                  \
      _Pragma("unroll") for (int c_ = 0; c_ < 5; ++c_) {                      \
        A0[c_] = 0.f; B0[c_] = 0.f;                                           \
      }                                                                       \
    }                                                                         \
    if (r0_ + 1 >= 0 && r0_ + 1 < H) {                                        \
      const float* p_ = P + (r0_ + 1) * W;                                    \
      const float* t_ = T + (r0_ + 1) * W;                                    \
      _Pragma("unroll") for (int c_ = 0; c_ < 5; ++c_) {                      \
        A1[c_] = p_[c_]; B1[c_] = t_[c_];                                     \
      }                                                                       \
    } else {                                                                  \
      _Pragma("unroll") for (int c_ = 0; c_ < 5; ++c_) {                      \
        A1[c_] = 0.f; B1[c_] = 0.f;                                           \
      }                                                                       \
    }                                                                         \
  } while (0)

// Load + pack a row-pair directly into ring slot J (preamble only).
#define LOADP_PACK(J, ROW)                                                    \
  do {                                                                        \
    float qa_[5], qb_[5], qc_[5], qd_[5];                                     \
    LOADP_RAW(ROW, qa_, qb_, qc_, qd_);                                       \
    _Pragma("unroll") for (int c_ = 0; c_ < 5; ++c_) {                        \
      rp[J][c_] = pack2(qa_[c_], qc_[c_]);                                    \
      rt[J][c_] = pack2(qb_[c_], qd_[c_]);                                    \
    }                                                                         \
  } while (0)

__global__ __launch_bounds__(256) void ssim_main(
    const float* __restrict__ pred, const float* __restrict__ targ,
    float* __restrict__ sink, int slotmask, int sstr) {
  const int lane = threadIdx.x & 63;
  const int wid  = threadIdx.x >> 6;
  const int stripe = blockIdx.x * WPB + wid;
  const int img = stripe / NSTRIPE;
  const int y0  = (stripe % NSTRIPE) * TH;

  const float* __restrict__ P = pred + (size_t)img * (W * H) + 5 * lane;
  const float* __restrict__ T = targ + (size_t)img * (W * H) + 5 * lane;

  // 11-tap Gaussian (sigma=1.5), normalized; f64-accurate literals.
  constexpr float WF[11] = {0.00102838f, 0.00759885f, 0.03600081f, 0.10936069f,
                            0.21300553f, 0.26601171f, 0.21300553f, 0.10936069f,
                            0.03600081f, 0.00759885f, 0.00102838f};
  // Row-A taps pair slot j -> weights (w[2j], w[2j+1]); row-B -> (w[2j-1], w[2j]).
  const h2 wAv[6] = {pack2(WF[0], WF[1]),  pack2(WF[2], WF[3]),
                     pack2(WF[4], WF[5]),  pack2(WF[6], WF[7]),
                     pack2(WF[8], WF[9]),  pack2(WF[10], 0.f)};
  const h2 wBv[6] = {pack2(0.f, WF[0]),    pack2(WF[1], WF[2]),
                     pack2(WF[3], WF[4]),  pack2(WF[5], WF[6]),
                     pack2(WF[7], WF[8]),  pack2(WF[9], WF[10])};
  h2 WH[11];
#pragma unroll
  for (int k = 0; k < 11; ++k) WH[k] = pack2(WF[k], WF[k]);

  // Ring of 6 row-pairs x 5 cols; (rowA,rowB) packed f16x2 per signal.
  h2 rp[6][5], rt[6][5];
  // Prefetched next pair, raw f32 (packed at next iteration's slide).
  float nfA[5], ntA[5], nfB[5], ntB[5];

  LOADP_PACK(1, y0 - 5);
  LOADP_PACK(2, y0 - 3);
  LOADP_PACK(3, y0 - 1);
  LOADP_PACK(4, y0 + 1);
  LOADP_PACK(5, y0 + 3);
  LOADP_RAW(y0 + 5, nfA, ntA, nfB, ntB);

  float acc = 0.f;
  const bool hasL = (lane >= 1), hasR = (lane <= 62);

#pragma unroll 1
  for (int it = 0; it < ITERS; ++it) {
    // Slide ring; pack last iteration's prefetch (vmcnt hidden by a full iter).
#pragma unroll
    for (int j = 0; j < 5; ++j)
#pragma unroll
      for (int c = 0; c < 5; ++c) {
        rp[j][c] = rp[j + 1][c];
        rt[j][c] = rt[j + 1][c];
      }
#pragma unroll
    for (int c = 0; c < 5; ++c) {
      rp[5][c] = pack2(nfA[c], nfB[c]);
      rt[5][c] = pack2(ntA[c], ntB[c]);
    }
    if (it + 1 < ITERS) LOADP_RAW(y0 + 2 * it + 7, nfA, ntA, nfB, ntB);

    // ---- vertical 11-tap blur, rows (y0+2it, y0+2it+1), 5 signals ----
    h2 PK[5][5];  // [ch][col], rows packed
#pragma unroll
    for (int c = 0; c < 5; ++c) {
      float mpA = 0, mtA = 0, ppA = 0, ttA = 0, ptA = 0;
      float mpB = 0, mtB = 0, ppB = 0, ttB = 0, ptB = 0;
#pragma unroll
      for (int j = 0; j < 6; ++j) {
        const h2 a = rp[j][c], b = rt[j][c];
        const h2 wa = wAv[j], wb = wBv[j];
        const h2 wpa = wa * a, wta = wa * b;
        const h2 wpb = wb * a, wtb = wb * b;
        mpA = fdot2f(wa, a, mpA);
        mtA = fdot2f(wa, b, mtA);
        ppA = fdot2f(wpa, a, ppA);
        ttA = fdot2f(wta, b, ttA);
        ptA = fdot2f(wpa, b, ptA);
        mpB = fdot2f(wb, a, mpB);
        mtB = fdot2f(wb, b, mtB);
        ppB = fdot2f(wpb, a, ppB);
        ttB = fdot2f(wtb, b, ttB);
        ptB = fdot2f(wpb, b, ptB);
      }
      PK[0][c] = pack2(mpA, mpB);
      PK[1][c] = pack2(mtA, mtB);
      PK[2][c] = pack2(ppA, ppB);
      PK[3][c] = pack2(ttA, ttB);
      PK[4][c] = pack2(ptA, ptB);
    }

    // ---- horizontal 11-tap blur, both rows at once (pk_fma) ----
    h2 OUT[5][5];
#pragma unroll
    for (int ch = 0; ch < 5; ++ch) {
      h2 ex[15];
#pragma unroll
      for (int c = 0; c < 5; ++c) {
        const int pv = __builtin_bit_cast(int, PK[ch][c]);
        const int u = __shfl_up(pv, 1, 64);
        const int d = __shfl_down(pv, 1, 64);
        ex[c]      = __builtin_bit_cast(h2, hasL ? u : 0);
        ex[5 + c]  = PK[ch][c];
        ex[10 + c] = __builtin_bit_cast(h2, hasR ? d : 0);
      }
#pragma unroll
      for (int c = 0; c < 5; ++c) {
        h2 s1 = WH[0] * ex[c];           // edge-inward: small weights first
#pragma unroll
        for (int k = 1; k < 5; ++k) s1 = WH[k] * ex[c + k] + s1;
        h2 s2 = WH[10] * ex[c + 10];
#pragma unroll
        for (int k = 9; k >= 5; --k) s2 = WH[k] * ex[c + k] + s2;
        OUT[ch][c] = s1 + s2;
      }
    }

    // ---- SSIM map + accumulate ----
#pragma unroll
    for (int c = 0; c < 5; ++c) {
#pragma unroll
      for (int r = 0; r < 2; ++r) {
        const float mx = r ? (float)OUT[0][c].y : (float)OUT[0][c].x;
        const float my = r ? (float)OUT[1][c].y : (float)OUT[1][c].x;
        const float xx = r ? (float)OUT[2][c].y : (float)OUT[2][c].x;
        const float yy = r ? (float)OUT[3][c].y : (float)OUT[3][c].x;
        const float xy = r ? (float)OUT[4][c].y : (float)OUT[4][c].x;
        const float mxx = mx * mx, myy = my * my, mxy = mx * my;
        const float vx = xx - mxx, vy = yy - myy, vxy = xy - mxy;
        const float num = (2.f * mxy + C1) * (2.f * vxy + C2);
        const float den = (mxx + myy + C1) * (vx + vy + C2);
        acc = fmaf(num, rcpf(den), acc);
      }
    }
  }

  // ---- wave reduce + spread atomics ----
#pragma unroll
  for (int off = 32; off; off >>= 1) acc += __shfl_xor(acc, off, 64);
  if (lane == 0) atomicAdd(sink + (stripe & slotmask) * sstr, acc);
}

__global__ void ssim_final(const float* __restrict__ sink, int nslot, int sstr,
                           float* __restrict__ out) {
  const int tid = threadIdx.x;  // 64 threads
  float v = 0.f;
  for (int s = tid; s < nslot; s += 64) v += sink[s * sstr];
#pragma unroll
  for (int off = 32; off; off >>= 1) v += __shfl_xor(v, off, 64);
  if (tid == 0) out[0] = 1.f - v / 13107200.f;
}

extern "C" void kernel_launch(void* const* d_in, const int* in_sizes, int n_in,
                              void* d_out, int out_size, void* d_ws, size_t ws_size,
                              hipStream_t stream) {
  (void)in_sizes; (void)n_in; (void)out_size;
  const float* pred = (const float*)d_in[0];
  const float* targ = (const float*)d_in[1];
  float* out = (float*)d_out;

  float* sink;
  int nslot, sstr;
  const size_t need = (size_t)NSLOT * SSTR * sizeof(float);
  if (ws_size >= need) {
    sink = (float*)d_ws;
    nslot = NSLOT;
    sstr = SSTR;
  } else {
    sink = out;   // fallback: single accumulator in d_out
    nslot = 1;
    sstr = 0;
  }
  hipMemsetAsync(sink, 0, nslot == 1 ? sizeof(float) : need, stream);
  ssim_main<<<dim3(NBLK), dim3(256), 0, stream>>>(pred, targ, sink, nslot - 1, sstr);
  ssim_final<<<1, 64, 0, stream>>>(sink, nslot, sstr, out);
}

// Round 5
// 62.620 us; speedup vs baseline: 3.1481x; 1.0268x over previous
//
#include <hip/hip_runtime.h>

// SSIM loss v5: wave-per-stripe TH=10 (4096 waves = exactly 16/CU resident),
// staggered preamble loads, channel-pipelined h-blur shuffles, 3-mul vertical.

namespace {
constexpr int W = 320, H = 320, B = 128;
constexpr int TH = 10;
constexpr int NSTRIPE = H / TH;     // 32
constexpr int WPB = 4;              // waves per block
constexpr int NWAVE = B * NSTRIPE;  // 4096
constexpr int NBLK = NWAVE / WPB;   // 1024 (= 4 blocks/CU, 16 waves/CU)
constexpr int ITERS = TH / 2;       // 5
constexpr float C1 = 1.0e-4f;
constexpr float C2 = 9.0e-4f;
constexpr int NSLOT = 128;
constexpr int SSTR = 16;
}

typedef _Float16 h2 __attribute__((ext_vector_type(2)));

__device__ __forceinline__ float fdot2f(h2 a, h2 b, float c) {
#if __has_builtin(__builtin_amdgcn_fdot2)
  return __builtin_amdgcn_fdot2(a, b, c, false);
#else
  return fmaf((float)a.x, (float)b.x, fmaf((float)a.y, (float)b.y, c));
#endif
}

__device__ __forceinline__ float rcpf(float x) {
  float r;
  asm("v_rcp_f32 %0, %1" : "=v"(r) : "v"(x));
  return r;
}

__device__ __forceinline__ h2 pack2(float a, float b) {
  return h2{(_Float16)a, (_Float16)b};
}

// Issue loads for one row-pair (both signals) into f32 temps, zero-padded.
#define LOADP_RAW(ROW, A0, B0, A1, B1)                                        \
  do {                                                                        \
    const int r0_ = (ROW);                                                    \
    if (r0_ >= 0 && r0_ < H) {                                                \
      const float* p_ = P + r0_ * W;                                          \
      const float* t_ = T + r0_ * W;                                          \
      _Pragma("unroll") for (int c_ = 0; c_ < 5; ++c_) {                      \
        A0[c_] = p_[c_]; B0[c_] = t_[c_];                                     \
      }                                                                       \
    } else {                                                                  \
      _Pragma("unroll") for (int c_ = 0; c_ < 5; ++c_) {                      \
        A0[c_] = 0.f; B0[c_] = 0.f;                                           \
      }                                                                       \
    }                                                                         \
    if (r0_ + 1 >= 0 && r0_ + 1 < H) {                                        \
      const float* p_ = P + (r0_ + 1) * W;                                    \
      const float* t_ = T + (r0_ + 1) * W;                                    \
      _Pragma("unroll") for (int c_ = 0; c_ < 5; ++c_) {                      \
        A1[c_] = p_[c_]; B1[c_] = t_[c_];                                     \
      }                                                                       \
    } else {                                                                  \
      _Pragma("unroll") for (int c_ = 0; c_ < 5; ++c_) {                      \
        A1[c_] = 0.f; B1[c_] = 0.f;                                           \
      }                                                                       \
    }                                                                         \
  } while (0)

// Pack f32 temps into ring slot J.
#define PACKTO(J, A0, B0, A1, B1)                                             \
  do {                                                                        \
    _Pragma("unroll") for (int c_ = 0; c_ < 5; ++c_) {                        \
      rp[J][c_] = pack2(A0[c_], A1[c_]);                                      \
      rt[J][c_] = pack2(B0[c_], B1[c_]);                                      \
    }                                                                         \
  } while (0)

// Halo shuffles for one channel (10 shfl + 10 cndmask).
#define SHFL(PKc, L, R)                                                       \
  do {                                                                        \
    _Pragma("unroll") for (int c_ = 0; c_ < 5; ++c_) {                        \
      const int pv_ = __builtin_bit_cast(int, PKc[c_]);                       \
      const int u_ = __shfl_up(pv_, 1, 64);                                   \
      const int d_ = __shfl_down(pv_, 1, 64);                                 \
      L[c_] = __builtin_bit_cast(h2, hasL ? u_ : 0);                          \
      R[c_] = __builtin_bit_cast(h2, hasR ? d_ : 0);                          \
    }                                                                         \
  } while (0)

// Horizontal 11-tap blur for one channel, both rows packed (55 pk_fma).
#define HBLUR(PKc, L, R, O)                                                   \
  do {                                                                        \
    _Pragma("unroll") for (int c_ = 0; c_ < 5; ++c_) {                        \
      h2 s1_ = WH[0] * ((c_ + 0 < 5) ? L[c_] : PKc[c_ - 5]);                  \
      _Pragma("unroll") for (int k_ = 1; k_ < 5; ++k_) {                      \
        const int i_ = c_ + k_;                                               \
        s1_ = WH[k_] * ((i_ < 5) ? L[i_] : PKc[i_ - 5]) + s1_;                \
      }                                                                       \
      h2 s2_ = WH[10] * ((c_ + 10 < 10) ? PKc[c_ + 5] : R[c_]);               \
      _Pragma("unroll") for (int k_ = 9; k_ >= 5; --k_) {                     \
        const int i_ = c_ + k_;                                               \
        s2_ = WH[k_] * ((i_ < 10) ? PKc[i_ - 5] : R[i_ - 10]) + s2_;          \
      }                                                                       \
      O[c_] = s1_ + s2_;                                                      \
    }                                                                         \
  } while (0)

__global__ __launch_bounds__(256) void ssim_main(
    const float* __restrict__ pred, const float* __restrict__ targ,
    float* __restrict__ sink, int slotmask, int sstr) {
  const int lane = threadIdx.x & 63;
  const int wid  = threadIdx.x >> 6;
  const int stripe = blockIdx.x * WPB + wid;
  const int img = stripe / NSTRIPE;
  const int y0  = (stripe % NSTRIPE) * TH;

  const float* __restrict__ P = pred + (size_t)img * (W * H) + 5 * lane;
  const float* __restrict__ T = targ + (size_t)img * (W * H) + 5 * lane;

  constexpr float WF[11] = {0.00102838f, 0.00759885f, 0.03600081f, 0.10936069f,
                            0.21300553f, 0.26601171f, 0.21300553f, 0.10936069f,
                            0.03600081f, 0.00759885f, 0.00102838f};
  const h2 wAv[6] = {pack2(WF[0], WF[1]),  pack2(WF[2], WF[3]),
                     pack2(WF[4], WF[5]),  pack2(WF[6], WF[7]),
                     pack2(WF[8], WF[9]),  pack2(WF[10], 0.f)};
  const h2 wBv[6] = {pack2(0.f, WF[0]),    pack2(WF[1], WF[2]),
                     pack2(WF[3], WF[4]),  pack2(WF[5], WF[6]),
                     pack2(WF[7], WF[8]),  pack2(WF[9], WF[10])};
  h2 WH[11];
#pragma unroll
  for (int k = 0; k < 11; ++k) WH[k] = pack2(WF[k], WF[k]);

  h2 rp[6][5], rt[6][5];
  float nfA[5], ntA[5], nfB[5], ntB[5];

  // ---- staggered preamble: 2 row-pairs in flight ----
  {
    float aA[5], bA[5], cA[5], dA[5];
    float aB[5], bB[5], cB[5], dB[5];
    LOADP_RAW(y0 - 5, aA, bA, cA, dA);   // p0
    LOADP_RAW(y0 - 3, aB, bB, cB, dB);   // p1
    PACKTO(1, aA, bA, cA, dA);
    LOADP_RAW(y0 - 1, aA, bA, cA, dA);   // p2
    PACKTO(2, aB, bB, cB, dB);
    LOADP_RAW(y0 + 1, aB, bB, cB, dB);   // p3
    PACKTO(3, aA, bA, cA, dA);
    LOADP_RAW(y0 + 3, aA, bA, cA, dA);   // p4
    PACKTO(4, aB, bB, cB, dB);
    LOADP_RAW(y0 + 5, nfA, ntA, nfB, ntB);  // p5 prefetch (packed in iter 0)
    PACKTO(5, aA, bA, cA, dA);
  }

  float acc = 0.f;
  const bool hasL = (lane >= 1), hasR = (lane <= 62);

#pragma unroll 1
  for (int it = 0; it < ITERS; ++it) {
    // slide ring; pack last iteration's prefetch; issue next loads.
#pragma unroll
    for (int j = 0; j < 5; ++j)
#pragma unroll
      for (int c = 0; c < 5; ++c) {
        rp[j][c] = rp[j + 1][c];
        rt[j][c] = rt[j + 1][c];
      }
    PACKTO(5, nfA, ntA, nfB, ntB);
    if (it + 1 < ITERS) LOADP_RAW(y0 + 2 * it + 7, nfA, ntA, nfB, ntB);

    // ---- vertical 11-tap blur (3 pk_mul + 10 dot2 per col-pair) ----
    h2 PK[5][5];  // [ch][col], two output rows packed
#pragma unroll
    for (int c = 0; c < 5; ++c) {
      float mpA = 0, mtA = 0, ppA = 0, ttA = 0, ptA = 0;
      float mpB = 0, mtB = 0, ppB = 0, ttB = 0, ptB = 0;
#pragma unroll
      for (int j = 0; j < 6; ++j) {
        const h2 a = rp[j][c], b = rt[j][c];
        const h2 aa = a * a, bb = b * b, ab = a * b;
        const h2 wa = wAv[j], wb = wBv[j];
        mpA = fdot2f(wa, a, mpA);
        mtA = fdot2f(wa, b, mtA);
        ppA = fdot2f(wa, aa, ppA);
        ttA = fdot2f(wa, bb, ttA);
        ptA = fdot2f(wa, ab, ptA);
        mpB = fdot2f(wb, a, mpB);
        mtB = fdot2f(wb, b, mtB);
        ppB = fdot2f(wb, aa, ppB);
        ttB = fdot2f(wb, bb, ttB);
        ptB = fdot2f(wb, ab, ptB);
      }
      PK[0][c] = pack2(mpA, mpB);
      PK[1][c] = pack2(mtA, mtB);
      PK[2][c] = pack2(ppA, ppB);
      PK[3][c] = pack2(ttA, ttB);
      PK[4][c] = pack2(ptA, ptB);
    }

    // ---- horizontal blur, shuffles pipelined one channel ahead ----
    h2 L0[5], R0[5], L1[5], R1[5];
    h2 OUT[5][5];
    SHFL(PK[0], L0, R0);
    SHFL(PK[1], L1, R1);
    HBLUR(PK[0], L0, R0, OUT[0]);
    SHFL(PK[2], L0, R0);
    HBLUR(PK[1], L1, R1, OUT[1]);
    SHFL(PK[3], L1, R1);
    HBLUR(PK[2], L0, R0, OUT[2]);
    SHFL(PK[4], L0, R0);
    HBLUR(PK[3], L1, R1, OUT[3]);
    HBLUR(PK[4], L0, R0, OUT[4]);

    // ---- SSIM map + accumulate ----
#pragma unroll
    for (int c = 0; c < 5; ++c) {
#pragma unroll
      for (int r = 0; r < 2; ++r) {
        const float mx = r ? (float)OUT[0][c].y : (float)OUT[0][c].x;
        const float my = r ? (float)OUT[1][c].y : (float)OUT[1][c].x;
        const float xx = r ? (float)OUT[2][c].y : (float)OUT[2][c].x;
        const float yy = r ? (float)OUT[3][c].y : (float)OUT[3][c].x;
        const float xy = r ? (float)OUT[4][c].y : (float)OUT[4][c].x;
        const float mxx = mx * mx, myy = my * my, mxy = mx * my;
        const float vx = xx - mxx, vy = yy - myy, vxy = xy - mxy;
        const float num = (2.f * mxy + C1) * (2.f * vxy + C2);
        const float den = (mxx + myy + C1) * (vx + vy + C2);
        acc = fmaf(num, rcpf(den), acc);
      }
    }
  }

  // ---- wave reduce + spread atomics ----
#pragma unroll
  for (int off = 32; off; off >>= 1) acc += __shfl_xor(acc, off, 64);
  if (lane == 0) atomicAdd(sink + (stripe & slotmask) * sstr, acc);
}

__global__ void ssim_final(const float* __restrict__ sink, int nslot, int sstr,
                           float* __restrict__ out) {
  const int tid = threadIdx.x;  // 64 threads
  float v = 0.f;
  for (int s = tid; s < nslot; s += 64) v += sink[s * sstr];
#pragma unroll
  for (int off = 32; off; off >>= 1) v += __shfl_xor(v, off, 64);
  if (tid == 0) out[0] = 1.f - v / 13107200.f;
}

extern "C" void kernel_launch(void* const* d_in, const int* in_sizes, int n_in,
                              void* d_out, int out_size, void* d_ws, size_t ws_size,
                              hipStream_t stream) {
  (void)in_sizes; (void)n_in; (void)out_size;
  const float* pred = (const float*)d_in[0];
  const float* targ = (const float*)d_in[1];
  float* out = (float*)d_out;

  float* sink;
  int nslot, sstr;
  const size_t need = (size_t)NSLOT * SSTR * sizeof(float);
  if (ws_size >= need) {
    sink = (float*)d_ws;
    nslot = NSLOT;
    sstr = SSTR;
  } else {
    sink = out;
    nslot = 1;
    sstr = 0;
  }
  hipMemsetAsync(sink, 0, nslot == 1 ? sizeof(float) : need, stream);
  ssim_main<<<dim3(NBLK), dim3(256), 0, stream>>>(pred, targ, sink, nslot - 1, sstr);
  ssim_final<<<1, 64, 0, stream>>>(sink, nslot, sstr, out);
}